// Round 1
// baseline (827.599 us; speedup 1.0000x reference)
//
#include <hip/hip_runtime.h>
#include <hip/hip_bf16.h>

// Problem constants
#define B_ 4
#define S_ 2048
#define D_ 1024
#define H_ 16
#define DK_ 64
#define MROWS (B_*S_)   // 8192

typedef unsigned short u16;
typedef __bf16 bf16x8 __attribute__((ext_vector_type(8)));
typedef float f32x4 __attribute__((ext_vector_type(4)));

// async global->LDS, 16B per lane, wave-uniform LDS base + lane*16
#define GLDS16(gp, lp) __builtin_amdgcn_global_load_lds( \
    (__attribute__((address_space(1))) void*)(gp), \
    (__attribute__((address_space(3))) void*)(lp), 16, 0, 0)

__device__ __forceinline__ bf16x8 frag_ld(const u16* p) {
    uint4 u = *reinterpret_cast<const uint4*>(p);
    return __builtin_bit_cast(bf16x8, u);
}
__device__ __forceinline__ u16 f2b(float f) {
    return __builtin_bit_cast(u16, __float2bfloat16(f));
}

// ---------------- fp32 -> bf16 convert ----------------
__global__ __launch_bounds__(256) void cvt_bf16(const float* __restrict__ s,
                                                u16* __restrict__ d, int n) {
    int i = (blockIdx.x * 256 + threadIdx.x) * 4;
    if (i >= n) return;
    float4 f = *reinterpret_cast<const float4*>(s + i);
    ushort4 u;
    u.x = f2b(f.x); u.y = f2b(f.y); u.z = f2b(f.z); u.w = f2b(f.w);
    *reinterpret_cast<ushort4*>(d + i) = u;
}

// ---------------- GEMM: C[M,N] = A[M,K] @ Bw[N,K]^T + bias ----------------
// MODE 0: write bf16 row-major [M][N]
// MODE 1: write bf16 per-head transposed Vt[(b*H+h)*64+d][S]
// MODE 2: write fp32 (acc + bias + resid) row-major
template <int MODE>
__global__ __launch_bounds__(256) void gemm_bt(
    const u16* __restrict__ A, const u16* __restrict__ Bw,
    const float* __restrict__ bias, const float* __restrict__ resid,
    u16* __restrict__ outb, float* __restrict__ outf)
{
    const int K = 1024, N = 1024;
    __shared__ u16 As[128 * 64] __attribute__((aligned(16)));
    __shared__ u16 Bs[128 * 64] __attribute__((aligned(16)));
    int lane = threadIdx.x & 63, wid = threadIdx.x >> 6;
    int wr = wid >> 1, wc = wid & 1;
    int l15 = lane & 15, l4 = lane >> 4;
    int row0 = blockIdx.y * 128, col0 = blockIdx.x * 128;
    int lrow = lane >> 3;          // 0..7 (row within 8-row block)
    int lcol = (lane & 7) * 8;     // element offset within 64-col row

    f32x4 acc[4][4] = {};

    for (int kt = 0; kt < K / 64; ++kt) {
        __syncthreads();
        const u16* Abase = A + (size_t)row0 * K + kt * 64;
        const u16* Bbase = Bw + (size_t)col0 * K + kt * 64;
#pragma unroll
        for (int c = 0; c < 4; ++c) {
            int blk = wid * 4 + c;             // 16 blocks of 8 rows
            GLDS16(Abase + (size_t)(blk * 8 + lrow) * K + lcol, As + blk * 512);
            GLDS16(Bbase + (size_t)(blk * 8 + lrow) * K + lcol, Bs + blk * 512);
        }
        __syncthreads();
#pragma unroll
        for (int kk = 0; kk < 2; ++kk) {
            bf16x8 af[4], bfv[4];
#pragma unroll
            for (int i = 0; i < 4; ++i)
                af[i] = frag_ld(As + (wr * 64 + i * 16 + l15) * 64 + kk * 32 + l4 * 8);
#pragma unroll
            for (int j = 0; j < 4; ++j)
                bfv[j] = frag_ld(Bs + (wc * 64 + j * 16 + l15) * 64 + kk * 32 + l4 * 8);
#pragma unroll
            for (int i = 0; i < 4; ++i)
#pragma unroll
                for (int j = 0; j < 4; ++j)
                    acc[i][j] = __builtin_amdgcn_mfma_f32_16x16x32_bf16(
                        af[i], bfv[j], acc[i][j], 0, 0, 0);
        }
    }

    // epilogue: C/D layout col = lane&15, row = (lane>>4)*4 + e
#pragma unroll
    for (int j = 0; j < 4; ++j) {
        int c = col0 + wc * 64 + j * 16 + l15;
        float bv = bias[c];
#pragma unroll
        for (int i = 0; i < 4; ++i) {
            int r = row0 + wr * 64 + i * 16 + l4 * 4;
            if (MODE == 0) {
#pragma unroll
                for (int e = 0; e < 4; ++e)
                    outb[(size_t)(r + e) * N + c] = f2b(acc[i][j][e] + bv);
            } else if (MODE == 1) {
                int h = c >> 6, dd = c & 63, bb = r >> 11, s = r & 2047;
                ushort4 u;
                u.x = f2b(acc[i][j][0] + bv);
                u.y = f2b(acc[i][j][1] + bv);
                u.z = f2b(acc[i][j][2] + bv);
                u.w = f2b(acc[i][j][3] + bv);
                *reinterpret_cast<ushort4*>(
                    outb + ((size_t)((bb * H_ + h) * DK_ + dd)) * S_ + s) = u;
            } else {
#pragma unroll
                for (int e = 0; e < 4; ++e) {
                    size_t idx = (size_t)(r + e) * N + c;
                    outf[idx] = acc[i][j][e] + bv + resid[idx];
                }
            }
        }
    }
}

// ---------------- fused attention (two-pass online softmax) ----------------
// grid: (S/128, H, B). 4 waves/block, each wave owns 32 q-rows.
__global__ __launch_bounds__(256) void attn_fused(
    const u16* __restrict__ Qb, const u16* __restrict__ Kb,
    const u16* __restrict__ Vt, const int* __restrict__ mask,
    float* __restrict__ attn_out, u16* __restrict__ ctx_out)
{
    __shared__ u16 Ks[64 * 64] __attribute__((aligned(16)));   // K chunk [s'][d]
    __shared__ u16 Vs[64 * 64] __attribute__((aligned(16)));   // Vt chunk [d][s']
    __shared__ u16 Pt[128 * 72] __attribute__((aligned(16)));  // bf16 P tile, padded

    int lane = threadIdx.x & 63, wid = threadIdx.x >> 6;
    int b = blockIdx.z, h = blockIdx.y;
    int q0 = blockIdx.x * 128 + wid * 32;
    int l15 = lane & 15, l4 = lane >> 4;
    int lrow = lane >> 3, lcol = (lane & 7) * 8;

    // Q fragments in registers (A-layout: row = lane&15, k = (lane>>4)*8)
    bf16x8 qf[2][2];
#pragma unroll
    for (int i = 0; i < 2; ++i)
#pragma unroll
        for (int kk = 0; kk < 2; ++kk)
            qf[i][kk] = frag_ld(Qb + (size_t)(b * S_ + q0 + i * 16 + l15) * D_ +
                                h * DK_ + kk * 32 + l4 * 8);

    float m_run[2][4], l_run[2][4];
#pragma unroll
    for (int i = 0; i < 2; ++i)
#pragma unroll
        for (int j = 0; j < 4; ++j) { m_run[i][j] = -3.0e38f; l_run[i][j] = 0.f; }

    // ---- PASS 1: row max / sum ----
    for (int c = 0; c < 32; ++c) {
        __syncthreads();
#pragma unroll
        for (int cc = 0; cc < 2; ++cc) {
            int blk = wid * 2 + cc;
            GLDS16(Kb + (size_t)(b * S_ + c * 64 + blk * 8 + lrow) * D_ + h * DK_ + lcol,
                   Ks + blk * 512);
        }
        __syncthreads();

        float sv[2][4][4];
#pragma unroll
        for (int n = 0; n < 4; ++n) {
            bool ok = mask[b * S_ + c * 64 + n * 16 + l15] != 0;
            bf16x8 kf0 = frag_ld(Ks + (n * 16 + l15) * 64 + l4 * 8);
            bf16x8 kf1 = frag_ld(Ks + (n * 16 + l15) * 64 + 32 + l4 * 8);
#pragma unroll
            for (int i = 0; i < 2; ++i) {
                f32x4 a = {};
                a = __builtin_amdgcn_mfma_f32_16x16x32_bf16(qf[i][0], kf0, a, 0, 0, 0);
                a = __builtin_amdgcn_mfma_f32_16x16x32_bf16(qf[i][1], kf1, a, 0, 0, 0);
#pragma unroll
                for (int j = 0; j < 4; ++j)
                    sv[i][n][j] = ok ? a[j] * 0.125f : -1.0e9f;
            }
        }
#pragma unroll
        for (int i = 0; i < 2; ++i)
#pragma unroll
            for (int j = 0; j < 4; ++j) {
                float mx = fmaxf(fmaxf(sv[i][0][j], sv[i][1][j]),
                                 fmaxf(sv[i][2][j], sv[i][3][j]));
                mx = fmaxf(mx, __shfl_xor(mx, 1));
                mx = fmaxf(mx, __shfl_xor(mx, 2));
                mx = fmaxf(mx, __shfl_xor(mx, 4));
                mx = fmaxf(mx, __shfl_xor(mx, 8));
                float mnew = fmaxf(m_run[i][j], mx);
                float p = __expf(sv[i][0][j] - mnew) + __expf(sv[i][1][j] - mnew) +
                          __expf(sv[i][2][j] - mnew) + __expf(sv[i][3][j] - mnew);
                p += __shfl_xor(p, 1);
                p += __shfl_xor(p, 2);
                p += __shfl_xor(p, 4);
                p += __shfl_xor(p, 8);
                l_run[i][j] = l_run[i][j] * __expf(m_run[i][j] - mnew) + p;
                m_run[i][j] = mnew;
            }
    }

    float inv_l[2][4];
#pragma unroll
    for (int i = 0; i < 2; ++i)
#pragma unroll
        for (int j = 0; j < 4; ++j) inv_l[i][j] = 1.0f / l_run[i][j];

    f32x4 cacc[2][4] = {};

    // ---- PASS 2: recompute, write attn, PV ----
    for (int c = 0; c < 32; ++c) {
        __syncthreads();
#pragma unroll
        for (int cc = 0; cc < 2; ++cc) {
            int blk = wid * 2 + cc;
            GLDS16(Kb + (size_t)(b * S_ + c * 64 + blk * 8 + lrow) * D_ + h * DK_ + lcol,
                   Ks + blk * 512);
            GLDS16(Vt + ((size_t)((b * H_ + h) * DK_ + blk * 8 + lrow)) * S_ + c * 64 + lcol,
                   Vs + blk * 512);
        }
        __syncthreads();

#pragma unroll
        for (int n = 0; n < 4; ++n) {
            bool ok = mask[b * S_ + c * 64 + n * 16 + l15] != 0;
            bf16x8 kf0 = frag_ld(Ks + (n * 16 + l15) * 64 + l4 * 8);
            bf16x8 kf1 = frag_ld(Ks + (n * 16 + l15) * 64 + 32 + l4 * 8);
#pragma unroll
            for (int i = 0; i < 2; ++i) {
                f32x4 a = {};
                a = __builtin_amdgcn_mfma_f32_16x16x32_bf16(qf[i][0], kf0, a, 0, 0, 0);
                a = __builtin_amdgcn_mfma_f32_16x16x32_bf16(qf[i][1], kf1, a, 0, 0, 0);
#pragma unroll
                for (int j = 0; j < 4; ++j) {
                    float s = ok ? a[j] * 0.125f : -1.0e9f;
                    float at = __expf(s - m_run[i][j]) * inv_l[i][j];
                    int qrow = q0 + i * 16 + l4 * 4 + j;
                    attn_out[((size_t)((b * H_ + h) * S_ + qrow)) * S_ + c * 64 + n * 16 + l15] = at;
                    Pt[(wid * 32 + i * 16 + l4 * 4 + j) * 72 + n * 16 + l15] = f2b(at);
                }
            }
        }
        // PV: ctx[q][d] += P[q][s'] * Vt[d][s']
#pragma unroll
        for (int kk = 0; kk < 2; ++kk) {
            bf16x8 pa[2];
#pragma unroll
            for (int i = 0; i < 2; ++i)
                pa[i] = frag_ld(Pt + (wid * 32 + i * 16 + l15) * 72 + kk * 32 + l4 * 8);
#pragma unroll
            for (int n = 0; n < 4; ++n) {
                bf16x8 vb = frag_ld(Vs + (n * 16 + l15) * 64 + kk * 32 + l4 * 8);
#pragma unroll
                for (int i = 0; i < 2; ++i)
                    cacc[i][n] = __builtin_amdgcn_mfma_f32_16x16x32_bf16(
                        pa[i], vb, cacc[i][n], 0, 0, 0);
            }
        }
    }

    // write ctx (bf16, [b][q][h*64+d])
#pragma unroll
    for (int i = 0; i < 2; ++i)
#pragma unroll
        for (int n = 0; n < 4; ++n)
#pragma unroll
            for (int j = 0; j < 4; ++j)
                ctx_out[(size_t)(b * S_ + q0 + i * 16 + l4 * 4 + j) * D_ +
                        h * DK_ + n * 16 + l15] = f2b(cacc[i][n][j]);
}

// ---------------- LayerNorm ----------------
__global__ __launch_bounds__(256) void ln_kernel(
    const float* __restrict__ X, const float* __restrict__ gamma,
    const float* __restrict__ beta, float* __restrict__ out)
{
    int row = blockIdx.x;
    int t = threadIdx.x;
    float4 v = *reinterpret_cast<const float4*>(X + (size_t)row * D_ + t * 4);
    float s = v.x + v.y + v.z + v.w;
    float ss = v.x * v.x + v.y * v.y + v.z * v.z + v.w * v.w;
#pragma unroll
    for (int o = 1; o < 64; o <<= 1) {
        s += __shfl_xor(s, o);
        ss += __shfl_xor(ss, o);
    }
    __shared__ float red[8];
    int wid = t >> 6, lane = t & 63;
    if (lane == 0) { red[wid] = s; red[wid + 4] = ss; }
    __syncthreads();
    s = red[0] + red[1] + red[2] + red[3];
    ss = red[4] + red[5] + red[6] + red[7];
    float mu = s * (1.0f / D_);
    float var = ss * (1.0f / D_) - mu * mu;
    float rs = rsqrtf(var + 1e-5f);
    float4 g = *reinterpret_cast<const float4*>(gamma + t * 4);
    float4 be = *reinterpret_cast<const float4*>(beta + t * 4);
    float4 o4;
    o4.x = (v.x - mu) * rs * g.x + be.x;
    o4.y = (v.y - mu) * rs * g.y + be.y;
    o4.z = (v.z - mu) * rs * g.z + be.z;
    o4.w = (v.w - mu) * rs * g.w + be.w;
    *reinterpret_cast<float4*>(out + (size_t)row * D_ + t * 4) = o4;
}

// ---------------- launch ----------------
extern "C" void kernel_launch(void* const* d_in, const int* in_sizes, int n_in,
                              void* d_out, int out_size, void* d_ws, size_t ws_size,
                              hipStream_t stream)
{
    const float* query = (const float*)d_in[0];
    const float* key   = (const float*)d_in[1];
    const float* value = (const float*)d_in[2];
    const int*   mask  = (const int*)d_in[3];
    const float* Wq = (const float*)d_in[4];
    const float* bq = (const float*)d_in[5];
    const float* Wk = (const float*)d_in[6];
    const float* bk = (const float*)d_in[7];
    const float* Wv = (const float*)d_in[8];
    const float* bv = (const float*)d_in[9];
    const float* Wo = (const float*)d_in[10];
    const float* bo = (const float*)d_in[11];
    const float* gamma = (const float*)d_in[12];
    const float* beta  = (const float*)d_in[13];

    char* w = (char*)d_ws;
    const size_t MB = 1024 * 1024;
    u16* xq = (u16*)(w);              // 16MB  (reused later for ctx)
    u16* xk = (u16*)(w + 16 * MB);    // 16MB  (reused later for x fp32)
    u16* xv = (u16*)(w + 32 * MB);    // 16MB  (reused later for x fp32)
    u16* wq = (u16*)(w + 48 * MB);
    u16* wk = (u16*)(w + 50 * MB);
    u16* wv = (u16*)(w + 52 * MB);
    u16* wo = (u16*)(w + 54 * MB);
    u16* qb = (u16*)(w + 56 * MB);
    u16* kb = (u16*)(w + 72 * MB);
    u16* vt = (u16*)(w + 88 * MB);
    u16* ctxb = (u16*)(w);            // reuse xq region
    float* xf = (float*)(w + 16 * MB); // reuse xk+xv regions (32MB)

    float* out0 = (float*)d_out;
    float* attn = (float*)d_out + (size_t)B_ * S_ * D_;

    int nBig = MROWS * D_;  // 8388608
    int nW = D_ * D_;       // 1048576

    cvt_bf16<<<nBig / 1024, 256, 0, stream>>>(query, xq, nBig);
    cvt_bf16<<<nBig / 1024, 256, 0, stream>>>(key,   xk, nBig);
    cvt_bf16<<<nBig / 1024, 256, 0, stream>>>(value, xv, nBig);
    cvt_bf16<<<nW / 1024, 256, 0, stream>>>(Wq, wq, nW);
    cvt_bf16<<<nW / 1024, 256, 0, stream>>>(Wk, wk, nW);
    cvt_bf16<<<nW / 1024, 256, 0, stream>>>(Wv, wv, nW);
    cvt_bf16<<<nW / 1024, 256, 0, stream>>>(Wo, wo, nW);

    dim3 gg(D_ / 128, MROWS / 128);  // (8, 64)
    gemm_bt<0><<<gg, 256, 0, stream>>>(xq, wq, bq, nullptr, qb, nullptr);
    gemm_bt<0><<<gg, 256, 0, stream>>>(xk, wk, bk, nullptr, kb, nullptr);
    gemm_bt<1><<<gg, 256, 0, stream>>>(xv, wv, bv, nullptr, vt, nullptr);

    dim3 ga(S_ / 128, H_, B_);
    attn_fused<<<ga, 256, 0, stream>>>(qb, kb, vt, mask, attn, ctxb);

    gemm_bt<2><<<gg, 256, 0, stream>>>(ctxb, wo, bo, query, nullptr, xf);
    ln_kernel<<<MROWS, 256, 0, stream>>>(xf, gamma, beta, out0);
}

// Round 2
// 824.079 us; speedup vs baseline: 1.0043x; 1.0043x over previous
//
#include <hip/hip_runtime.h>
#include <hip/hip_bf16.h>

// Problem constants
#define B_ 4
#define S_ 2048
#define D_ 1024
#define H_ 16
#define DK_ 64
#define MROWS (B_*S_)   // 8192

typedef unsigned short u16;
typedef __bf16 bf16x8 __attribute__((ext_vector_type(8)));
typedef float f32x4 __attribute__((ext_vector_type(4)));

// async global->LDS, 16B per lane, wave-uniform LDS base + lane*16
#define GLDS16(gp, lp) __builtin_amdgcn_global_load_lds( \
    (__attribute__((address_space(1))) void*)(gp), \
    (__attribute__((address_space(3))) void*)(lp), 16, 0, 0)

__device__ __forceinline__ bf16x8 frag_ld(const u16* p) {
    uint4 u = *reinterpret_cast<const uint4*>(p);
    return __builtin_bit_cast(bf16x8, u);
}
__device__ __forceinline__ u16 f2b(float f) {
    return __builtin_bit_cast(u16, __float2bfloat16(f));
}

// ---------------- fp32 -> bf16 convert ----------------
__global__ __launch_bounds__(256) void cvt_bf16(const float* __restrict__ s,
                                                u16* __restrict__ d, int n) {
    int i = (blockIdx.x * 256 + threadIdx.x) * 4;
    if (i >= n) return;
    float4 f = *reinterpret_cast<const float4*>(s + i);
    ushort4 u;
    u.x = f2b(f.x); u.y = f2b(f.y); u.z = f2b(f.z); u.w = f2b(f.w);
    *reinterpret_cast<ushort4*>(d + i) = u;
}

// ---------------- GEMM: C[M,N] = A[M,K] @ Bw[N,K]^T + bias ----------------
// MODE 0: write bf16 row-major [M][N]
// MODE 1: write bf16 per-head transposed Vt[(b*H+h)*64+d][S]
// MODE 2: write fp32 (acc + bias + resid) row-major
template <int MODE>
__global__ __launch_bounds__(256) void gemm_bt(
    const u16* __restrict__ A, const u16* __restrict__ Bw,
    const float* __restrict__ bias, const float* __restrict__ resid,
    u16* __restrict__ outb, float* __restrict__ outf)
{
    const int K = 1024, N = 1024;
    __shared__ u16 As[128 * 64] __attribute__((aligned(16)));
    __shared__ u16 Bs[128 * 64] __attribute__((aligned(16)));
    int lane = threadIdx.x & 63, wid = threadIdx.x >> 6;
    int wr = wid >> 1, wc = wid & 1;
    int l15 = lane & 15, l4 = lane >> 4;
    int row0 = blockIdx.y * 128, col0 = blockIdx.x * 128;
    int lrow = lane >> 3;          // 0..7 (row within 8-row block)
    int lcol = (lane & 7) * 8;     // element offset within 64-col row

    f32x4 acc[4][4] = {};

    for (int kt = 0; kt < K / 64; ++kt) {
        __syncthreads();
        const u16* Abase = A + (size_t)row0 * K + kt * 64;
        const u16* Bbase = Bw + (size_t)col0 * K + kt * 64;
#pragma unroll
        for (int c = 0; c < 4; ++c) {
            int blk = wid * 4 + c;             // 16 blocks of 8 rows
            GLDS16(Abase + (size_t)(blk * 8 + lrow) * K + lcol, As + blk * 512);
            GLDS16(Bbase + (size_t)(blk * 8 + lrow) * K + lcol, Bs + blk * 512);
        }
        __syncthreads();
#pragma unroll
        for (int kk = 0; kk < 2; ++kk) {
            bf16x8 af[4], bfv[4];
#pragma unroll
            for (int i = 0; i < 4; ++i)
                af[i] = frag_ld(As + (wr * 64 + i * 16 + l15) * 64 + kk * 32 + l4 * 8);
#pragma unroll
            for (int j = 0; j < 4; ++j)
                bfv[j] = frag_ld(Bs + (wc * 64 + j * 16 + l15) * 64 + kk * 32 + l4 * 8);
#pragma unroll
            for (int i = 0; i < 4; ++i)
#pragma unroll
                for (int j = 0; j < 4; ++j)
                    acc[i][j] = __builtin_amdgcn_mfma_f32_16x16x32_bf16(
                        af[i], bfv[j], acc[i][j], 0, 0, 0);
        }
    }

    // epilogue: C/D layout col = lane&15, row = (lane>>4)*4 + e
#pragma unroll
    for (int j = 0; j < 4; ++j) {
        int c = col0 + wc * 64 + j * 16 + l15;
        float bv = bias[c];
#pragma unroll
        for (int i = 0; i < 4; ++i) {
            int r = row0 + wr * 64 + i * 16 + l4 * 4;
            if (MODE == 0) {
#pragma unroll
                for (int e = 0; e < 4; ++e)
                    outb[(size_t)(r + e) * N + c] = f2b(acc[i][j][e] + bv);
            } else if (MODE == 1) {
                int h = c >> 6, dd = c & 63, bb = r >> 11, s = r & 2047;
                ushort4 u;
                u.x = f2b(acc[i][j][0] + bv);
                u.y = f2b(acc[i][j][1] + bv);
                u.z = f2b(acc[i][j][2] + bv);
                u.w = f2b(acc[i][j][3] + bv);
                *reinterpret_cast<ushort4*>(
                    outb + ((size_t)((bb * H_ + h) * DK_ + dd)) * S_ + s) = u;
            } else {
#pragma unroll
                for (int e = 0; e < 4; ++e) {
                    size_t idx = (size_t)(r + e) * N + c;
                    outf[idx] = acc[i][j][e] + bv + resid[idx];
                }
            }
        }
    }
}

// ---------------- fused attention (two-pass online softmax) ----------------
// grid: (S/128, H, B). 4 waves/block, each wave owns 32 q-rows.
__global__ __launch_bounds__(256) void attn_fused(
    const u16* __restrict__ Qb, const u16* __restrict__ Kb,
    const u16* __restrict__ Vt, const int* __restrict__ mask,
    float* __restrict__ attn_out, u16* __restrict__ ctx_out)
{
    __shared__ u16 Ks[64 * 64] __attribute__((aligned(16)));   // K chunk [s'][d]
    __shared__ u16 Vs[64 * 64] __attribute__((aligned(16)));   // Vt chunk [d][s']
    __shared__ u16 Pt[128 * 72] __attribute__((aligned(16)));  // bf16 P tile, padded

    int lane = threadIdx.x & 63, wid = threadIdx.x >> 6;
    int b = blockIdx.z, h = blockIdx.y;
    int q0 = blockIdx.x * 128 + wid * 32;
    int l15 = lane & 15, l4 = lane >> 4;
    int lrow = lane >> 3, lcol = (lane & 7) * 8;

    // Q fragments in registers (A-layout: row = lane&15, k = (lane>>4)*8)
    bf16x8 qf[2][2];
#pragma unroll
    for (int i = 0; i < 2; ++i)
#pragma unroll
        for (int kk = 0; kk < 2; ++kk)
            qf[i][kk] = frag_ld(Qb + (size_t)(b * S_ + q0 + i * 16 + l15) * D_ +
                                h * DK_ + kk * 32 + l4 * 8);

    float m_run[2][4], l_run[2][4];
#pragma unroll
    for (int i = 0; i < 2; ++i)
#pragma unroll
        for (int j = 0; j < 4; ++j) { m_run[i][j] = -3.0e38f; l_run[i][j] = 0.f; }

    // ---- PASS 1: row max / sum ----
    for (int c = 0; c < 32; ++c) {
        __syncthreads();
#pragma unroll
        for (int cc = 0; cc < 2; ++cc) {
            int blk = wid * 2 + cc;
            GLDS16(Kb + (size_t)(b * S_ + c * 64 + blk * 8 + lrow) * D_ + h * DK_ + lcol,
                   Ks + blk * 512);
        }
        __syncthreads();

        float sv[2][4][4];
#pragma unroll
        for (int n = 0; n < 4; ++n) {
            bool ok = mask[b * S_ + c * 64 + n * 16 + l15] != 0;
            bf16x8 kf0 = frag_ld(Ks + (n * 16 + l15) * 64 + l4 * 8);
            bf16x8 kf1 = frag_ld(Ks + (n * 16 + l15) * 64 + 32 + l4 * 8);
#pragma unroll
            for (int i = 0; i < 2; ++i) {
                f32x4 a = {};
                a = __builtin_amdgcn_mfma_f32_16x16x32_bf16(qf[i][0], kf0, a, 0, 0, 0);
                a = __builtin_amdgcn_mfma_f32_16x16x32_bf16(qf[i][1], kf1, a, 0, 0, 0);
#pragma unroll
                for (int j = 0; j < 4; ++j)
                    sv[i][n][j] = ok ? a[j] * 0.125f : -1.0e9f;
            }
        }
#pragma unroll
        for (int i = 0; i < 2; ++i)
#pragma unroll
            for (int j = 0; j < 4; ++j) {
                float mx = fmaxf(fmaxf(sv[i][0][j], sv[i][1][j]),
                                 fmaxf(sv[i][2][j], sv[i][3][j]));
                mx = fmaxf(mx, __shfl_xor(mx, 1));
                mx = fmaxf(mx, __shfl_xor(mx, 2));
                mx = fmaxf(mx, __shfl_xor(mx, 4));
                mx = fmaxf(mx, __shfl_xor(mx, 8));
                float mnew = fmaxf(m_run[i][j], mx);
                float p = __expf(sv[i][0][j] - mnew) + __expf(sv[i][1][j] - mnew) +
                          __expf(sv[i][2][j] - mnew) + __expf(sv[i][3][j] - mnew);
                p += __shfl_xor(p, 1);
                p += __shfl_xor(p, 2);
                p += __shfl_xor(p, 4);
                p += __shfl_xor(p, 8);
                l_run[i][j] = l_run[i][j] * __expf(m_run[i][j] - mnew) + p;
                m_run[i][j] = mnew;
            }
    }

    float inv_l[2][4];
#pragma unroll
    for (int i = 0; i < 2; ++i)
#pragma unroll
        for (int j = 0; j < 4; ++j) inv_l[i][j] = 1.0f / l_run[i][j];

    f32x4 cacc[2][4] = {};

    // ---- PASS 2: recompute, write attn, PV ----
    for (int c = 0; c < 32; ++c) {
        __syncthreads();
#pragma unroll
        for (int cc = 0; cc < 2; ++cc) {
            int blk = wid * 2 + cc;
            GLDS16(Kb + (size_t)(b * S_ + c * 64 + blk * 8 + lrow) * D_ + h * DK_ + lcol,
                   Ks + blk * 512);
            GLDS16(Vt + ((size_t)((b * H_ + h) * DK_ + blk * 8 + lrow)) * S_ + c * 64 + lcol,
                   Vs + blk * 512);
        }
        __syncthreads();

#pragma unroll
        for (int n = 0; n < 4; ++n) {
            bool ok = mask[b * S_ + c * 64 + n * 16 + l15] != 0;
            bf16x8 kf0 = frag_ld(Ks + (n * 16 + l15) * 64 + l4 * 8);
            bf16x8 kf1 = frag_ld(Ks + (n * 16 + l15) * 64 + 32 + l4 * 8);
#pragma unroll
            for (int i = 0; i < 2; ++i) {
                f32x4 a = {};
                a = __builtin_amdgcn_mfma_f32_16x16x32_bf16(qf[i][0], kf0, a, 0, 0, 0);
                a = __builtin_amdgcn_mfma_f32_16x16x32_bf16(qf[i][1], kf1, a, 0, 0, 0);
#pragma unroll
                for (int j = 0; j < 4; ++j) {
                    float s = ok ? a[j] * 0.125f : -1.0e9f;
                    float at = __expf(s - m_run[i][j]) * inv_l[i][j];
                    int qrow = q0 + i * 16 + l4 * 4 + j;
                    attn_out[((size_t)((b * H_ + h) * S_ + qrow)) * S_ + c * 64 + n * 16 + l15] = at;
                    Pt[(wid * 32 + i * 16 + l4 * 4 + j) * 72 + n * 16 + l15] = f2b(at);
                }
            }
        }
        // PV: ctx[q][d] += P[q][s'] * Vt[d][s']
#pragma unroll
        for (int kk = 0; kk < 2; ++kk) {
            bf16x8 pa[2];
#pragma unroll
            for (int i = 0; i < 2; ++i)
                pa[i] = frag_ld(Pt + (wid * 32 + i * 16 + l15) * 72 + kk * 32 + l4 * 8);
#pragma unroll
            for (int n = 0; n < 4; ++n) {
                bf16x8 vb = frag_ld(Vs + (n * 16 + l15) * 64 + kk * 32 + l4 * 8);
#pragma unroll
                for (int i = 0; i < 2; ++i)
                    cacc[i][n] = __builtin_amdgcn_mfma_f32_16x16x32_bf16(
                        pa[i], vb, cacc[i][n], 0, 0, 0);
            }
        }
    }

    // write ctx (bf16, [b][q][h*64+d])
#pragma unroll
    for (int i = 0; i < 2; ++i)
#pragma unroll
        for (int n = 0; n < 4; ++n)
#pragma unroll
            for (int j = 0; j < 4; ++j)
                ctx_out[(size_t)(b * S_ + q0 + i * 16 + l4 * 4 + j) * D_ +
                        h * DK_ + n * 16 + l15] = f2b(cacc[i][n][j]);
}

// ---------------- LayerNorm ----------------
__global__ __launch_bounds__(256) void ln_kernel(
    const float* __restrict__ X, const float* __restrict__ gamma,
    const float* __restrict__ beta, float* __restrict__ out)
{
    int row = blockIdx.x;
    int t = threadIdx.x;
    float4 v = *reinterpret_cast<const float4*>(X + (size_t)row * D_ + t * 4);
    float s = v.x + v.y + v.z + v.w;
    float ss = v.x * v.x + v.y * v.y + v.z * v.z + v.w * v.w;
#pragma unroll
    for (int o = 1; o < 64; o <<= 1) {
        s += __shfl_xor(s, o);
        ss += __shfl_xor(ss, o);
    }
    __shared__ float red[8];
    int wid = t >> 6, lane = t & 63;
    if (lane == 0) { red[wid] = s; red[wid + 4] = ss; }
    __syncthreads();
    s = red[0] + red[1] + red[2] + red[3];
    ss = red[4] + red[5] + red[6] + red[7];
    float mu = s * (1.0f / D_);
    float var = ss * (1.0f / D_) - mu * mu;
    float rs = rsqrtf(var + 1e-5f);
    float4 g = *reinterpret_cast<const float4*>(gamma + t * 4);
    float4 be = *reinterpret_cast<const float4*>(beta + t * 4);
    float4 o4;
    o4.x = (v.x - mu) * rs * g.x + be.x;
    o4.y = (v.y - mu) * rs * g.y + be.y;
    o4.z = (v.z - mu) * rs * g.z + be.z;
    o4.w = (v.w - mu) * rs * g.w + be.w;
    *reinterpret_cast<float4*>(out + (size_t)row * D_ + t * 4) = o4;
}

// ---------------- launch ----------------
extern "C" void kernel_launch(void* const* d_in, const int* in_sizes, int n_in,
                              void* d_out, int out_size, void* d_ws, size_t ws_size,
                              hipStream_t stream)
{
    const float* query = (const float*)d_in[0];
    const float* key   = (const float*)d_in[1];
    const float* value = (const float*)d_in[2];
    const int*   mask  = (const int*)d_in[3];
    const float* Wq = (const float*)d_in[4];
    const float* bq = (const float*)d_in[5];
    const float* Wk = (const float*)d_in[6];
    const float* bk = (const float*)d_in[7];
    const float* Wv = (const float*)d_in[8];
    const float* bv = (const float*)d_in[9];
    const float* Wo = (const float*)d_in[10];
    const float* bo = (const float*)d_in[11];
    const float* gamma = (const float*)d_in[12];
    const float* beta  = (const float*)d_in[13];

    char* w = (char*)d_ws;
    const size_t MB = 1024 * 1024;
    u16* xq = (u16*)(w);              // 16MB  (reused later for ctx)
    u16* xk = (u16*)(w + 16 * MB);    // 16MB  (reused later for x fp32)
    u16* xv = (u16*)(w + 32 * MB);    // 16MB  (reused later for x fp32)
    u16* wq = (u16*)(w + 48 * MB);
    u16* wk = (u16*)(w + 50 * MB);
    u16* wv = (u16*)(w + 52 * MB);
    u16* wo = (u16*)(w + 54 * MB);
    u16* qb = (u16*)(w + 56 * MB);
    u16* kb = (u16*)(w + 72 * MB);
    u16* vt = (u16*)(w + 88 * MB);
    u16* ctxb = (u16*)(w);            // reuse xq region
    float* xf = (float*)(w + 16 * MB); // reuse xk+xv regions (32MB)

    float* out0 = (float*)d_out;
    float* attn = (float*)d_out + (size_t)B_ * S_ * D_;

    int nBig = MROWS * D_;  // 8388608
    int nW = D_ * D_;       // 1048576

    cvt_bf16<<<nBig / 1024, 256, 0, stream>>>(query, xq, nBig);
    cvt_bf16<<<nBig / 1024, 256, 0, stream>>>(key,   xk, nBig);
    cvt_bf16<<<nBig / 1024, 256, 0, stream>>>(value, xv, nBig);
    cvt_bf16<<<nW / 1024, 256, 0, stream>>>(Wq, wq, nW);
    cvt_bf16<<<nW / 1024, 256, 0, stream>>>(Wk, wk, nW);
    cvt_bf16<<<nW / 1024, 256, 0, stream>>>(Wv, wv, nW);
    cvt_bf16<<<nW / 1024, 256, 0, stream>>>(Wo, wo, nW);

    dim3 gg(D_ / 128, MROWS / 128);  // (8, 64)
    gemm_bt<0><<<gg, 256, 0, stream>>>(xq, wq, bq, nullptr, qb, nullptr);
    gemm_bt<0><<<gg, 256, 0, stream>>>(xk, wk, bk, nullptr, kb, nullptr);
    gemm_bt<1><<<gg, 256, 0, stream>>>(xv, wv, bv, nullptr, vt, nullptr);

    dim3 ga(S_ / 128, H_, B_);
    attn_fused<<<ga, 256, 0, stream>>>(qb, kb, vt, mask, attn, ctxb);

    gemm_bt<2><<<gg, 256, 0, stream>>>(ctxb, wo, bo, query, nullptr, xf);
    ln_kernel<<<MROWS, 256, 0, stream>>>(xf, gamma, beta, out0);
}